// Round 21
// baseline (880.290 us; speedup 1.0000x reference)
//
#include <hip/hip_runtime.h>
#include <stdint.h>

#define T_LEN 8196
#define LOG2E 1.4426950408889634f
#define LN2   0.6931471805599453f
#define INF2  1.4426950e10f   /* 1e10 * log2(e): INF in base-2-scaled units */
#define PD_LD 2080            /* padded E row stride: 16 left + 2048 + 16 right */
#define PD_OFF 16

// ---------------------------------------------------------------- helpers
__device__ __forceinline__ float fexp2(float x) {
#if __has_builtin(__builtin_amdgcn_exp2f)
    return __builtin_amdgcn_exp2f(x);
#else
    return __expf(x * LN2);
#endif
}
__device__ __forceinline__ float flog2(float x) {
#if __has_builtin(__builtin_amdgcn_logf)
    return __builtin_amdgcn_logf(x);   // v_log_f32 is base-2
#else
    return __logf(x) * LOG2E;
#endif
}
__device__ __forceinline__ float sigm(float x) { return 1.0f / (1.0f + __expf(-x)); }
__device__ __forceinline__ float tanh_f(float x) {
    x = fminf(fmaxf(x, -15.0f), 15.0f);
    float e = __expf(2.0f * x);
    return (e - 1.0f) / (e + 1.0f);
}

// ------------------------------------------- prep: transpose weights
// [kc][gate(3)][u(128)][ki(4)] -- lane u reads ONE float4 covering 4
// consecutive k for one gate (coalesced 1KB/wave-load).
__global__ void k_prep(const float* __restrict__ Wih1, const float* __restrict__ Whh1,
                       const float* __restrict__ Wih2, const float* __restrict__ Whh2,
                       float* __restrict__ wt) {
    int gid = blockIdx.x * 256 + threadIdx.x;
    if (gid >= 175104) return;
    const float* src;
    int r, K;
    if (gid < 27648)       { r = gid;          K = 72;  src = Wih1; }
    else if (gid < 76800)  { r = gid - 27648;  K = 128; src = Whh1; }
    else if (gid < 125952) { r = gid - 76800;  K = 128; src = Wih2; }
    else                   { r = gid - 125952; K = 128; src = Whh2; }
    int kc   = r / 1536;
    int rem  = r - kc * 1536;
    int gate = rem >> 9;
    int rem2 = rem & 511;
    int u    = rem2 >> 2;
    int ki   = rem2 & 3;
    wt[gid] = src[(gate * 128 + u) * K + kc * 4 + ki];
}

// ------------------------------------------- GRU features (R22, proven ~200us)
// 512 blocks x 256 threads x 4 win/thread + k-chunked float4 weights with
// "#pragma unroll 1" on kc loops (prevents the R21 full-unroll VGPR blowup).
__global__ __launch_bounds__(256)
void k_gru(const float* __restrict__ X, const float* __restrict__ Y,
           const float* __restrict__ wt,
           const float* __restrict__ bih1, const float* __restrict__ bhh1,
           const float* __restrict__ bih2, const float* __restrict__ bhh2,
           const float* __restrict__ W1, const float* __restrict__ b1,
           float* __restrict__ fbuf) {
    __shared__ __align__(16) float xb[72 * 12];
    __shared__ __align__(16) float h1l[128 * 12];
    __shared__ __align__(16) float h2l[128 * 12];

    const int tid = threadIdx.x;
    const int u = tid & 127;
    const int w0 = (tid >> 7) * 4;
    const int bx = blockIdx.x;
    const int seq = bx >> 8;
    const int wbase = (bx & 255) << 3;
    const float* xp = seq ? Y : X;

    const float* wih1 = wt;
    const float* whh1 = wt + 27648;
    const float* wih2 = wt + 76800;
    const float* whh2 = wt + 125952;
    const int u4 = u << 2;

    const float br1  = bih1[u] + bhh1[u];
    const float bz1  = bih1[128 + u] + bhh1[128 + u];
    const float bni1 = bih1[256 + u];
    const float bnh1 = bhh1[256 + u];
    const float br2  = bih2[u] + bhh2[u];
    const float bz2  = bih2[128 + u] + bhh2[128 + u];
    const float bni2 = bih2[256 + u];
    const float bnh2 = bhh2[256 + u];

    float h1r[4], h2r[4];
#pragma unroll
    for (int j = 0; j < 4; ++j) { h1r[j] = 0.f; h2r[j] = 0.f; }
    for (int e = tid; e < 128 * 12; e += 256) { h1l[e] = 0.f; h2l[e] = 0.f; }
    __syncthreads();

    for (int t = 0; t < 8; ++t) {
        for (int e = tid; e < 72 * 8; e += 256) {
            int k = e >> 3, w = e & 7;
            int jj = k / 3, c = k - jj * 3;
            xb[k * 12 + w] = xp[jj * (3 * T_LEN) + c * T_LEN + ((wbase + w) << 2) + t];
        }
        __syncthreads();

        float ar[4], az[4], ai[4], ah[4];
#pragma unroll
        for (int j = 0; j < 4; ++j) { ar[j] = br1; az[j] = bz1; ai[j] = bni1; ah[j] = bnh1; }
#pragma unroll 1
        for (int kc = 0; kc < 18; ++kc) {
            const float4 wr4 = *(const float4*)&wih1[kc * 1536 + u4];
            const float4 wz4 = *(const float4*)&wih1[kc * 1536 + 512 + u4];
            const float4 wn4 = *(const float4*)&wih1[kc * 1536 + 1024 + u4];
            const float wrk[4] = {wr4.x, wr4.y, wr4.z, wr4.w};
            const float wzk[4] = {wz4.x, wz4.y, wz4.z, wz4.w};
            const float wnk[4] = {wn4.x, wn4.y, wn4.z, wn4.w};
#pragma unroll
            for (int ki = 0; ki < 4; ++ki) {
                const float4 x0 = *(const float4*)&xb[(kc * 4 + ki) * 12 + w0];
                float xv[4] = {x0.x, x0.y, x0.z, x0.w};
#pragma unroll
                for (int j = 0; j < 4; ++j) {
                    ar[j] = fmaf(wrk[ki], xv[j], ar[j]);
                    az[j] = fmaf(wzk[ki], xv[j], az[j]);
                    ai[j] = fmaf(wnk[ki], xv[j], ai[j]);
                }
            }
        }
#pragma unroll 1
        for (int kc = 0; kc < 32; ++kc) {
            const float4 wr4 = *(const float4*)&whh1[kc * 1536 + u4];
            const float4 wz4 = *(const float4*)&whh1[kc * 1536 + 512 + u4];
            const float4 wn4 = *(const float4*)&whh1[kc * 1536 + 1024 + u4];
            const float wrk[4] = {wr4.x, wr4.y, wr4.z, wr4.w};
            const float wzk[4] = {wz4.x, wz4.y, wz4.z, wz4.w};
            const float wnk[4] = {wn4.x, wn4.y, wn4.z, wn4.w};
#pragma unroll
            for (int ki = 0; ki < 4; ++ki) {
                const float4 x0 = *(const float4*)&h1l[(kc * 4 + ki) * 12 + w0];
                float xv[4] = {x0.x, x0.y, x0.z, x0.w};
#pragma unroll
                for (int j = 0; j < 4; ++j) {
                    ar[j] = fmaf(wrk[ki], xv[j], ar[j]);
                    az[j] = fmaf(wzk[ki], xv[j], az[j]);
                    ah[j] = fmaf(wnk[ki], xv[j], ah[j]);
                }
            }
        }
        __syncthreads();
#pragma unroll
        for (int j = 0; j < 4; ++j) {
            float r = sigm(ar[j]);
            float z = sigm(az[j]);
            float n = tanh_f(ai[j] + r * ah[j]);
            h1r[j] = (1.f - z) * n + z * h1r[j];
        }
#pragma unroll
        for (int j = 0; j < 4; ++j) h1l[u * 12 + w0 + j] = h1r[j];
        __syncthreads();

#pragma unroll
        for (int j = 0; j < 4; ++j) { ar[j] = br2; az[j] = bz2; ai[j] = bni2; ah[j] = bnh2; }
#pragma unroll 1
        for (int kc = 0; kc < 32; ++kc) {
            const float4 wr4 = *(const float4*)&wih2[kc * 1536 + u4];
            const float4 wz4 = *(const float4*)&wih2[kc * 1536 + 512 + u4];
            const float4 wn4 = *(const float4*)&wih2[kc * 1536 + 1024 + u4];
            const float wrk[4] = {wr4.x, wr4.y, wr4.z, wr4.w};
            const float wzk[4] = {wz4.x, wz4.y, wz4.z, wz4.w};
            const float wnk[4] = {wn4.x, wn4.y, wn4.z, wn4.w};
#pragma unroll
            for (int ki = 0; ki < 4; ++ki) {
                const float4 x0 = *(const float4*)&h1l[(kc * 4 + ki) * 12 + w0];
                float xv[4] = {x0.x, x0.y, x0.z, x0.w};
#pragma unroll
                for (int j = 0; j < 4; ++j) {
                    ar[j] = fmaf(wrk[ki], xv[j], ar[j]);
                    az[j] = fmaf(wzk[ki], xv[j], az[j]);
                    ai[j] = fmaf(wnk[ki], xv[j], ai[j]);
                }
            }
        }
#pragma unroll 1
        for (int kc = 0; kc < 32; ++kc) {
            const float4 wr4 = *(const float4*)&whh2[kc * 1536 + u4];
            const float4 wz4 = *(const float4*)&whh2[kc * 1536 + 512 + u4];
            const float4 wn4 = *(const float4*)&whh2[kc * 1536 + 1024 + u4];
            const float wrk[4] = {wr4.x, wr4.y, wr4.z, wr4.w};
            const float wzk[4] = {wz4.x, wz4.y, wz4.z, wz4.w};
            const float wnk[4] = {wn4.x, wn4.y, wn4.z, wn4.w};
#pragma unroll
            for (int ki = 0; ki < 4; ++ki) {
                const float4 x0 = *(const float4*)&h2l[(kc * 4 + ki) * 12 + w0];
                float xv[4] = {x0.x, x0.y, x0.z, x0.w};
#pragma unroll
                for (int j = 0; j < 4; ++j) {
                    ar[j] = fmaf(wrk[ki], xv[j], ar[j]);
                    az[j] = fmaf(wzk[ki], xv[j], az[j]);
                    ah[j] = fmaf(wnk[ki], xv[j], ah[j]);
                }
            }
        }
        __syncthreads();
#pragma unroll
        for (int j = 0; j < 4; ++j) {
            float r = sigm(ar[j]);
            float z = sigm(az[j]);
            float n = tanh_f(ai[j] + r * ah[j]);
            h2r[j] = (1.f - z) * n + z * h2r[j];
        }
#pragma unroll
        for (int j = 0; j < 4; ++j) h2l[u * 12 + w0 + j] = h2r[j];
        __syncthreads();
    }

    for (int idx = tid; idx < 8 * 30; idx += 256) {
        int w = idx / 30, ff = idx - w * 30;
        float acc = b1[ff];
        for (int k = 0; k < 128; ++k) acc = fmaf(h2l[k * 12 + w], W1[ff * 128 + k], acc);
        fbuf[(seq * 2048 + wbase + w) * 32 + ff] = acc;
    }
}

// ------------------------------------------- pairwise sqdist -> E = exp(-D), padded
__global__ __launch_bounds__(256)
void k_pair(const float* __restrict__ fbuf, float* __restrict__ Ep) {
    __shared__ float f1t[64 * 33];
    __shared__ float f2t[64 * 33];
    const int tid = threadIdx.x;
    const int i0 = blockIdx.y * 64, j0 = blockIdx.x * 64;
    for (int e = tid; e < 64 * 32; e += 256) {
        int r = e >> 5, c = e & 31;
        f1t[r * 33 + c] = fbuf[(i0 + r) * 32 + c];
        f2t[r * 33 + c] = fbuf[(2048 + j0 + r) * 32 + c];
    }
    __syncthreads();
    const int tx = tid & 15, ty = tid >> 4;
    float acc[4][4];
#pragma unroll
    for (int r = 0; r < 4; ++r)
#pragma unroll
        for (int c = 0; c < 4; ++c) acc[r][c] = 0.f;
    for (int k = 0; k < 30; ++k) {
        float a[4], b[4];
#pragma unroll
        for (int r = 0; r < 4; ++r) a[r] = f1t[(ty * 4 + r) * 33 + k];
#pragma unroll
        for (int c = 0; c < 4; ++c) b[c] = f2t[(tx * 4 + c) * 33 + k];
#pragma unroll
        for (int r = 0; r < 4; ++r)
#pragma unroll
            for (int c = 0; c < 4; ++c) {
                float d = a[r] - b[c];
                acc[r][c] = fmaf(d, d, acc[r][c]);
            }
    }
#pragma unroll
    for (int r = 0; r < 4; ++r) {
        float4 v = make_float4(__expf(-acc[r][0]), __expf(-acc[r][1]),
                               __expf(-acc[r][2]), __expf(-acc[r][3]));
        *(float4*)&Ep[(size_t)(i0 + ty * 4 + r) * PD_LD + PD_OFF + j0 + tx * 4] = v;
    }
}

// ------------------------------------------- softDTW wavefront, EXP-DOMAIN
// R27 = R26 compute core (2-col skew + Sc guard, slack tag 31) with
// PRODUCER-CONSUMER WAVE SPECIALIZATION for the E tiles:
//  * wave1 (tid 64..127) streams tiles 0..272 into a 4-deep LDS ring via
//    reg-staged loads; all VMEM latency lives on wave1.
//  * wave0 (tid 0..63) acquire-spins flg[m&3]==q+1 (steady state: one LDS
//    broadcast load -- wave1 runs ~4 tiles ahead), 8x ds_read_b128, then
//    releases the buffer (cns) and runs the unchanged R26 macro math.
//  * R13..R23 diagnosis: single-wave schedules expose ~1600cy/macro of
//    global-load latency (folded reg buffers / hard vmcnt waits). Moving
//    tile traffic to a second wave removes it from the critical path.
#define DTW_GROUP(G, CT)                                                         \
  {                                                                              \
    float inA, inB, dgl;                                                         \
    if (lane == 0) {                                                             \
        inA = sIn[2 * (G)]; inB = sIn[2 * (G) + 1];                              \
        dgl = ((G) == 0) ? carryA : sIn[2 * (G) - 1];                            \
    } else { inA = pA; inB = pB; dgl = dgPrev; }                                 \
    {   /* mid-macro overflow guard */                                           \
        float mnG = fminf(fminf(inA, inB), dgl);                                 \
        float lim = mnG + 100.f;                                                 \
        if (Sc > lim) {                                                          \
            int ddg = (int)fmaxf(lim - Sc, -2.0e9f);                             \
            W0 = ldexpf(W0, ddg); W1 = ldexpf(W1, ddg);                          \
            W2 = ldexpf(W2, ddg); W3 = ldexpf(W3, ddg);                          \
            Sc = lim;                                                            \
        }                                                                        \
    }                                                                            \
    float ua = fexp2(Sc - inA);                                                  \
    float ub = fexp2(Sc - inB);                                                  \
    float da = fexp2(Sc - dgl);                                                  \
    float eA0 = CT[0][2*(G)],   eA1 = CT[1][2*(G)];                              \
    float eA2 = CT[2][2*(G)],   eA3 = CT[3][2*(G)];                              \
    float eB0 = CT[0][2*(G)+1], eB1 = CT[1][2*(G)+1];                            \
    float eB2 = CT[2][2*(G)+1], eB3 = CT[3][2*(G)+1];                            \
    float oA0 = eA0 * (da + W0);                                                 \
    float oA1 = eA1 * (W0 + W1);                                                 \
    float oA2 = eA2 * (W1 + W2);                                                 \
    float oA3 = eA3 * (W2 + W3);                                                 \
    float a0 = fmaf(eA0, ua, oA0);                                               \
    float a1 = fmaf(eA1, a0, oA1);                                               \
    float a2 = fmaf(eA2, a1, oA2);                                               \
    float a3 = fmaf(eA3, a2, oA3);                                               \
    float oB0 = eB0 * (ua + a0);                                                 \
    float oB1 = eB1 * (a0 + a1);                                                 \
    float oB2 = eB2 * (a1 + a2);                                                 \
    float oB3 = eB3 * (a2 + a3);                                                 \
    float b0 = fmaf(eB0, ub, oB0);                                               \
    float b1 = fmaf(eB1, b0, oB1);                                               \
    float b2 = fmaf(eB2, b1, oB2);                                               \
    float b3 = fmaf(eB3, b2, oB3);                                               \
    W0 = b0; W1 = b1; W2 = b2; W3 = b3;                                          \
    float blogA = fminf(Sc - flog2(a3), INF2);                                   \
    float blogB = fminf(Sc - flog2(b3), INF2);                                   \
    blog[2 * (G)] = blogA; blog[2 * (G) + 1] = blogB;                            \
    float sA = __shfl_up(blogA, 1);                                              \
    float sB = __shfl_up(blogB, 1);                                              \
    dgPrev = pB; pA = sA; pB = sB;                                               \
    mnAcc = fminf(mnAcc, fminf(sA, sB));                                         \
  }

#define DTW_MACRO(PVC, PVI, M)                                                   \
  {                                                                              \
    const int m = (M);                                                           \
    const int bf = m & 3;                                                        \
    const int q  = m >> 2;                                                       \
    while (__hip_atomic_load(&flg[bf], __ATOMIC_ACQUIRE,                         \
                             __HIP_MEMORY_SCOPE_WORKGROUP) != q + 1)             \
        __builtin_amdgcn_s_sleep(2);                                             \
    float eT[4][8];                                                              \
    {                                                                            \
        const float* cb = &ldsE[bf][lane * 4];                                   \
        _Pragma("unroll")                                                        \
        for (int r = 0; r < 4; ++r) {                                            \
            float4 lo = *(const float4*)&cb[(2 * r) * 256];                      \
            float4 hi = *(const float4*)&cb[(2 * r + 1) * 256];                  \
            eT[r][0]=lo.x; eT[r][1]=lo.y; eT[r][2]=lo.z; eT[r][3]=lo.w;          \
            eT[r][4]=hi.x; eT[r][5]=hi.y; eT[r][6]=hi.z; eT[r][7]=hi.w;          \
        }                                                                        \
    }                                                                            \
    if (lane == 0)                                                               \
        __hip_atomic_store(&cns[bf], q + 1, __ATOMIC_RELEASE,                    \
                           __HIP_MEMORY_SCOPE_WORKGROUP);                        \
    if (b > 0 && lane == 0) {   /* issue boundary loads for macro m+3 */         \
        _Pragma("unroll")                                                        \
        for (int u = 0; u < 8; ++u) {                                            \
            int jc = 8 * (m + 3) + u; jc = jc > 2047 ? 2047 : jc;                \
            PVI[u] = __hip_atomic_load(&bIn[jc], __ATOMIC_RELAXED,               \
                                       __HIP_MEMORY_SCOPE_AGENT);                \
        }                                                                        \
    }                                                                            \
    float blog[8];                                                               \
    float mnAcc = INF2;                                                          \
    DTW_GROUP(0, eT) DTW_GROUP(1, eT) DTW_GROUP(2, eT) DTW_GROUP(3, eT)          \
    carryA = sIn[7];                                                             \
    if (lane == 63) {                                                            \
        if (b < 7) {                                                             \
            _Pragma("unroll")                                                    \
            for (int c = 0; c < 8; ++c) {                                        \
                int j = 8 * m + c - 126;                                         \
                if (j >= 0 && j < 2048) {                                        \
                    uint64_t pk = ((uint64_t)(uint32_t)j << 32) |                \
                                  (uint64_t)__float_as_uint(blog[c]);            \
                    (void)__hip_atomic_exchange(&bOut[j], pk, __ATOMIC_RELAXED,  \
                                                __HIP_MEMORY_SCOPE_AGENT);       \
                }                                                                \
            }                                                                    \
        } else if (m == 271) {   /* col 8*271+5-126 == 2047 */                   \
            res = blog[5];                                                       \
        }                                                                        \
    }                                                                            \
    if (b > 0 && lane == 0) {   /* consume ring slot PVC = boundary for m+1 */   \
        bool again = false;                                                      \
        _Pragma("unroll")                                                        \
        for (int u = 0; u < 8; ++u) {                                            \
            int jc = 8 * (m + 1) + u; jc = jc > 2047 ? 2047 : jc;                \
            if ((uint32_t)(PVC[u] >> 32) != (uint32_t)jc) again = true;          \
        }                                                                        \
        while (again) {   /* frontier contact: fine-grained backoff */           \
            __builtin_amdgcn_s_sleep(2);                                         \
            _Pragma("unroll")                                                    \
            for (int u = 0; u < 8; ++u) {                                        \
                int jc = 8 * (m + 1) + u; jc = jc > 2047 ? 2047 : jc;            \
                PVC[u] = __hip_atomic_load(&bIn[jc], __ATOMIC_RELAXED,           \
                                           __HIP_MEMORY_SCOPE_AGENT);            \
            }                                                                    \
            again = false;                                                       \
            _Pragma("unroll")                                                    \
            for (int u = 0; u < 8; ++u) {                                        \
                int jc = 8 * (m + 1) + u; jc = jc > 2047 ? 2047 : jc;            \
                if ((uint32_t)(PVC[u] >> 32) != (uint32_t)jc) again = true;      \
            }                                                                    \
        }                                                                        \
        _Pragma("unroll")                                                        \
        for (int u = 0; u < 8; ++u) sIn[u] = __uint_as_float((uint32_t)PVC[u]);  \
    }                                                                            \
    { /* scale update */                                                         \
        float mn = mnAcc;                                                        \
        if (lane == 0) {                                                         \
            if (b > 0) {                                                         \
                mn = sIn[0];                                                     \
                _Pragma("unroll")                                                \
                for (int c = 1; c < 8; ++c) mn = fminf(mn, sIn[c]);              \
            } else {                                                             \
                mn = INF2;                                                       \
            }                                                                    \
        }                                                                        \
        float wmax = fmaxf(fmaxf(W0, W1), fmaxf(W2, W3));                        \
        float Sc_new;                                                            \
        if (wmax > 0.f) {                                                        \
            int e = (int)((__float_as_uint(wmax) >> 23) & 0xFFu) - 127;          \
            Sc_new = fminf(Sc - (float)e, mn + 100.f);                           \
        } else {                                                                 \
            Sc_new = fminf(mn, 1e9f);                                            \
        }                                                                        \
        int dd = (int)fmaxf(fminf(Sc_new - Sc, 999.f), -999.f);                  \
        W0 = ldexpf(W0, dd); W1 = ldexpf(W1, dd);                                \
        W2 = ldexpf(W2, dd); W3 = ldexpf(W3, dd);                                \
        Sc = Sc_new;                                                             \
    }                                                                            \
  }

__global__ __launch_bounds__(128)
void k_dtw(const float* __restrict__ Ep, uint64_t* bndG, float* __restrict__ out) {
    __shared__ __align__(16) float ldsE[4][2048];   // 4-deep tile ring (32 KB)
    __shared__ int flg[4];   // per-buffer write count
    __shared__ int cns[4];   // per-buffer consume count

    const int b = blockIdx.x;
    const int tid = threadIdx.x;
    const int lane = tid & 63;

    if (tid < 4) { flg[tid] = 0; cns[tid] = 0; }
    __syncthreads();

    if (tid >= 64) {
        // ================= wave1: tile prefetcher =================
        const int r0 = b * 256 + lane * 4;
        const float* rp[4];
#pragma unroll
        for (int r = 0; r < 4; ++r) rp[r] = Ep + (size_t)(r0 + r) * PD_LD + PD_OFF;
        for (int m = 0; m <= 272; ++m) {
            const int bf = m & 3, q = m >> 2;
            while (__hip_atomic_load(&cns[bf], __ATOMIC_ACQUIRE,
                                     __HIP_MEMORY_SCOPE_WORKGROUP) != q)
                __builtin_amdgcn_s_sleep(2);
            int bs = 8 * m - 2 * lane;
            bs = bs < -16 ? -16 : (bs > 2048 ? 2048 : bs);
            float* dst = &ldsE[bf][lane * 4];
#pragma unroll
            for (int r = 0; r < 4; ++r) {
#pragma unroll
                for (int h = 0; h < 2; ++h) {
                    float2 v0 = *(const float2*)(rp[r] + bs + 4 * h);
                    float2 v1 = *(const float2*)(rp[r] + bs + 4 * h + 2);
                    *(float4*)&dst[(2 * r + h) * 256] =
                        make_float4(v0.x, v0.y, v1.x, v1.y);
                }
            }
            if (lane == 0)
                __hip_atomic_store(&flg[bf], q + 1, __ATOMIC_RELEASE,
                                   __HIP_MEMORY_SCOPE_WORKGROUP);
        }
        return;
    }

    // ================= wave0: compute (R26 core) =================
    const uint64_t* bIn = bndG + (size_t)(b - 1) * 2048;
    uint64_t* bOut = bndG + (size_t)b * 2048;

    float W0 = 0.f, W1 = 0.f, W2 = 0.f, W3 = 0.f;
    float Sc = 0.f;
    float carryA = (b == 0 && lane == 0) ? 0.f : INF2;  // seed: A(-1,-1)=0
    float res = 0.f;
    float pA = INF2, pB = INF2, dgPrev = INF2;          // pending shfl pair (log)
    float sIn[8];
#pragma unroll
    for (int c = 0; c < 8; ++c) sIn[c] = INF2;

    uint64_t pvs0[8], pvs1[8], pvs2[8];
#pragma unroll
    for (int u = 0; u < 8; ++u) { pvs0[u] = 0; pvs1[u] = 0; pvs2[u] = 0; }

    if (b > 0 && lane == 0) {
        // --- startup SLACK: wait until producer is ~19.5 macros ahead
        //     (col 31 written by b-1 at its macro 19 under the 2-col skew)
        {
            uint64_t p = __hip_atomic_load(&bIn[31], __ATOMIC_RELAXED,
                                           __HIP_MEMORY_SCOPE_AGENT);
            while ((uint32_t)(p >> 32) != 31u) {
                __builtin_amdgcn_s_sleep(8);
                p = __hip_atomic_load(&bIn[31], __ATOMIC_RELAXED,
                                      __HIP_MEMORY_SCOPE_AGENT);
            }
        }
        // --- blocking poll for macro-0 boundary (cols 0..7) + scale seed
        uint64_t pv[8];
        bool again = true;
        while (again) {
#pragma unroll
            for (int u = 0; u < 8; ++u)
                pv[u] = __hip_atomic_load(&bIn[u], __ATOMIC_RELAXED,
                                          __HIP_MEMORY_SCOPE_AGENT);
            again = false;
#pragma unroll
            for (int u = 0; u < 8; ++u)
                if ((uint32_t)(pv[u] >> 32) != (uint32_t)u) again = true;
            if (again) __builtin_amdgcn_s_sleep(2);
        }
        float mn = INF2;
#pragma unroll
        for (int u = 0; u < 8; ++u) {
            sIn[u] = __uint_as_float((uint32_t)pv[u]);
            mn = fminf(mn, sIn[u]);
        }
        Sc = fminf(mn, 1e9f);
        // --- prime ring: targets macro 1 (cols 8..15) and macro 2 (16..23)
#pragma unroll
        for (int u = 0; u < 8; ++u)
            pvs1[u] = __hip_atomic_load(&bIn[8 + u], __ATOMIC_RELAXED,
                                        __HIP_MEMORY_SCOPE_AGENT);
#pragma unroll
        for (int u = 0; u < 8; ++u)
            pvs2[u] = __hip_atomic_load(&bIn[16 + u], __ATOMIC_RELAXED,
                                        __HIP_MEMORY_SCOPE_AGENT);
    }

    // 273 macro-steps of 8 cols (lane63 hits col 2047 at m=271)
    for (int mm = 0; mm < 273; mm += 3) {
        DTW_MACRO(pvs1, pvs0, mm);
        DTW_MACRO(pvs2, pvs1, mm + 1);
        DTW_MACRO(pvs0, pvs2, mm + 2);
    }

    if (b == 7 && lane == 63) out[0] = res * LN2;   // back to base-e units
}

// ------------------------------------------- launch
extern "C" void kernel_launch(void* const* d_in, const int* in_sizes, int n_in,
                              void* d_out, int out_size, void* d_ws, size_t ws_size,
                              hipStream_t stream) {
    const float* X    = (const float*)d_in[0];
    const float* Y    = (const float*)d_in[1];
    const float* Wih1 = (const float*)d_in[2];
    const float* Whh1 = (const float*)d_in[3];
    const float* bih1 = (const float*)d_in[4];
    const float* bhh1 = (const float*)d_in[5];
    const float* Wih2 = (const float*)d_in[6];
    const float* Whh2 = (const float*)d_in[7];
    const float* bih2 = (const float*)d_in[8];
    const float* bhh2 = (const float*)d_in[9];
    const float* W1   = (const float*)d_in[10];
    const float* b1   = (const float*)d_in[11];
    float* out = (float*)d_out;

    // Layout (floats). wt overlaps Ep's tail (dead after k_gru; k_pair
    // overwrites all of Ep afterwards). ~17.7 MB total.
    float* ws   = (float*)d_ws;
    float* fbuf = ws;                            // 131072 floats
    uint64_t* bndG = (uint64_t*)(ws + 131072);   // 7*2048 u64 = 28672 floats
    float* Ep   = ws + 131072 + 28672;           // 2048*2080 = 4259840 floats
    float* wt   = Ep + 4259840 - 175104;         // overlapped tail

    k_prep<<<684, 256, 0, stream>>>(Wih1, Whh1, Wih2, Whh2, wt);
    k_gru<<<512, 256, 0, stream>>>(X, Y, wt, bih1, bhh1, bih2, bhh2, W1, b1, fbuf);
    k_pair<<<dim3(32, 32), 256, 0, stream>>>(fbuf, Ep);
    k_dtw<<<8, 128, 0, stream>>>(Ep, bndG, out);
}

// Round 22
// 756.251 us; speedup vs baseline: 1.1640x; 1.1640x over previous
//
#include <hip/hip_runtime.h>
#include <stdint.h>

#define T_LEN 8196
#define LOG2E 1.4426950408889634f
#define LN2   0.6931471805599453f
#define INF2  1.4426950e10f   /* 1e10 * log2(e): INF in base-2-scaled units */
#define PD_LD 2080            /* padded E row stride: 16 left + 2048 + 16 right */
#define PD_OFF 16

// ---------------------------------------------------------------- helpers
__device__ __forceinline__ float fexp2(float x) {
#if __has_builtin(__builtin_amdgcn_exp2f)
    return __builtin_amdgcn_exp2f(x);
#else
    return __expf(x * LN2);
#endif
}
__device__ __forceinline__ float flog2(float x) {
#if __has_builtin(__builtin_amdgcn_logf)
    return __builtin_amdgcn_logf(x);   // v_log_f32 is base-2
#else
    return __logf(x) * LOG2E;
#endif
}
__device__ __forceinline__ float sigm(float x) { return 1.0f / (1.0f + __expf(-x)); }
__device__ __forceinline__ float tanh_f(float x) {
    x = fminf(fmaxf(x, -15.0f), 15.0f);
    float e = __expf(2.0f * x);
    return (e - 1.0f) / (e + 1.0f);
}

// ------------------------------------------- prep: transpose weights
// [kc][gate(3)][u(128)][ki(4)] -- lane u reads ONE float4 covering 4
// consecutive k for one gate (coalesced 1KB/wave-load).
__global__ void k_prep(const float* __restrict__ Wih1, const float* __restrict__ Whh1,
                       const float* __restrict__ Wih2, const float* __restrict__ Whh2,
                       float* __restrict__ wt) {
    int gid = blockIdx.x * 256 + threadIdx.x;
    if (gid >= 175104) return;
    const float* src;
    int r, K;
    if (gid < 27648)       { r = gid;          K = 72;  src = Wih1; }
    else if (gid < 76800)  { r = gid - 27648;  K = 128; src = Whh1; }
    else if (gid < 125952) { r = gid - 76800;  K = 128; src = Wih2; }
    else                   { r = gid - 125952; K = 128; src = Whh2; }
    int kc   = r / 1536;
    int rem  = r - kc * 1536;
    int gate = rem >> 9;
    int rem2 = rem & 511;
    int u    = rem2 >> 2;
    int ki   = rem2 & 3;
    wt[gid] = src[(gate * 128 + u) * K + kc * 4 + ki];
}

// ------------------------------------------- GRU features (R22, proven ~200us)
// 512 blocks x 256 threads x 4 win/thread + k-chunked float4 weights with
// "#pragma unroll 1" on kc loops (prevents the R21 full-unroll VGPR blowup).
__global__ __launch_bounds__(256)
void k_gru(const float* __restrict__ X, const float* __restrict__ Y,
           const float* __restrict__ wt,
           const float* __restrict__ bih1, const float* __restrict__ bhh1,
           const float* __restrict__ bih2, const float* __restrict__ bhh2,
           const float* __restrict__ W1, const float* __restrict__ b1,
           float* __restrict__ fbuf) {
    __shared__ __align__(16) float xb[72 * 12];
    __shared__ __align__(16) float h1l[128 * 12];
    __shared__ __align__(16) float h2l[128 * 12];

    const int tid = threadIdx.x;
    const int u = tid & 127;
    const int w0 = (tid >> 7) * 4;
    const int bx = blockIdx.x;
    const int seq = bx >> 8;
    const int wbase = (bx & 255) << 3;
    const float* xp = seq ? Y : X;

    const float* wih1 = wt;
    const float* whh1 = wt + 27648;
    const float* wih2 = wt + 76800;
    const float* whh2 = wt + 125952;
    const int u4 = u << 2;

    const float br1  = bih1[u] + bhh1[u];
    const float bz1  = bih1[128 + u] + bhh1[128 + u];
    const float bni1 = bih1[256 + u];
    const float bnh1 = bhh1[256 + u];
    const float br2  = bih2[u] + bhh2[u];
    const float bz2  = bih2[128 + u] + bhh2[128 + u];
    const float bni2 = bih2[256 + u];
    const float bnh2 = bhh2[256 + u];

    float h1r[4], h2r[4];
#pragma unroll
    for (int j = 0; j < 4; ++j) { h1r[j] = 0.f; h2r[j] = 0.f; }
    for (int e = tid; e < 128 * 12; e += 256) { h1l[e] = 0.f; h2l[e] = 0.f; }
    __syncthreads();

    for (int t = 0; t < 8; ++t) {
        for (int e = tid; e < 72 * 8; e += 256) {
            int k = e >> 3, w = e & 7;
            int jj = k / 3, c = k - jj * 3;
            xb[k * 12 + w] = xp[jj * (3 * T_LEN) + c * T_LEN + ((wbase + w) << 2) + t];
        }
        __syncthreads();

        float ar[4], az[4], ai[4], ah[4];
#pragma unroll
        for (int j = 0; j < 4; ++j) { ar[j] = br1; az[j] = bz1; ai[j] = bni1; ah[j] = bnh1; }
#pragma unroll 1
        for (int kc = 0; kc < 18; ++kc) {
            const float4 wr4 = *(const float4*)&wih1[kc * 1536 + u4];
            const float4 wz4 = *(const float4*)&wih1[kc * 1536 + 512 + u4];
            const float4 wn4 = *(const float4*)&wih1[kc * 1536 + 1024 + u4];
            const float wrk[4] = {wr4.x, wr4.y, wr4.z, wr4.w};
            const float wzk[4] = {wz4.x, wz4.y, wz4.z, wz4.w};
            const float wnk[4] = {wn4.x, wn4.y, wn4.z, wn4.w};
#pragma unroll
            for (int ki = 0; ki < 4; ++ki) {
                const float4 x0 = *(const float4*)&xb[(kc * 4 + ki) * 12 + w0];
                float xv[4] = {x0.x, x0.y, x0.z, x0.w};
#pragma unroll
                for (int j = 0; j < 4; ++j) {
                    ar[j] = fmaf(wrk[ki], xv[j], ar[j]);
                    az[j] = fmaf(wzk[ki], xv[j], az[j]);
                    ai[j] = fmaf(wnk[ki], xv[j], ai[j]);
                }
            }
        }
#pragma unroll 1
        for (int kc = 0; kc < 32; ++kc) {
            const float4 wr4 = *(const float4*)&whh1[kc * 1536 + u4];
            const float4 wz4 = *(const float4*)&whh1[kc * 1536 + 512 + u4];
            const float4 wn4 = *(const float4*)&whh1[kc * 1536 + 1024 + u4];
            const float wrk[4] = {wr4.x, wr4.y, wr4.z, wr4.w};
            const float wzk[4] = {wz4.x, wz4.y, wz4.z, wz4.w};
            const float wnk[4] = {wn4.x, wn4.y, wn4.z, wn4.w};
#pragma unroll
            for (int ki = 0; ki < 4; ++ki) {
                const float4 x0 = *(const float4*)&h1l[(kc * 4 + ki) * 12 + w0];
                float xv[4] = {x0.x, x0.y, x0.z, x0.w};
#pragma unroll
                for (int j = 0; j < 4; ++j) {
                    ar[j] = fmaf(wrk[ki], xv[j], ar[j]);
                    az[j] = fmaf(wzk[ki], xv[j], az[j]);
                    ah[j] = fmaf(wnk[ki], xv[j], ah[j]);
                }
            }
        }
        __syncthreads();
#pragma unroll
        for (int j = 0; j < 4; ++j) {
            float r = sigm(ar[j]);
            float z = sigm(az[j]);
            float n = tanh_f(ai[j] + r * ah[j]);
            h1r[j] = (1.f - z) * n + z * h1r[j];
        }
#pragma unroll
        for (int j = 0; j < 4; ++j) h1l[u * 12 + w0 + j] = h1r[j];
        __syncthreads();

#pragma unroll
        for (int j = 0; j < 4; ++j) { ar[j] = br2; az[j] = bz2; ai[j] = bni2; ah[j] = bnh2; }
#pragma unroll 1
        for (int kc = 0; kc < 32; ++kc) {
            const float4 wr4 = *(const float4*)&wih2[kc * 1536 + u4];
            const float4 wz4 = *(const float4*)&wih2[kc * 1536 + 512 + u4];
            const float4 wn4 = *(const float4*)&wih2[kc * 1536 + 1024 + u4];
            const float wrk[4] = {wr4.x, wr4.y, wr4.z, wr4.w};
            const float wzk[4] = {wz4.x, wz4.y, wz4.z, wz4.w};
            const float wnk[4] = {wn4.x, wn4.y, wn4.z, wn4.w};
#pragma unroll
            for (int ki = 0; ki < 4; ++ki) {
                const float4 x0 = *(const float4*)&h1l[(kc * 4 + ki) * 12 + w0];
                float xv[4] = {x0.x, x0.y, x0.z, x0.w};
#pragma unroll
                for (int j = 0; j < 4; ++j) {
                    ar[j] = fmaf(wrk[ki], xv[j], ar[j]);
                    az[j] = fmaf(wzk[ki], xv[j], az[j]);
                    ai[j] = fmaf(wnk[ki], xv[j], ai[j]);
                }
            }
        }
#pragma unroll 1
        for (int kc = 0; kc < 32; ++kc) {
            const float4 wr4 = *(const float4*)&whh2[kc * 1536 + u4];
            const float4 wz4 = *(const float4*)&whh2[kc * 1536 + 512 + u4];
            const float4 wn4 = *(const float4*)&whh2[kc * 1536 + 1024 + u4];
            const float wrk[4] = {wr4.x, wr4.y, wr4.z, wr4.w};
            const float wzk[4] = {wz4.x, wz4.y, wz4.z, wz4.w};
            const float wnk[4] = {wn4.x, wn4.y, wn4.z, wn4.w};
#pragma unroll
            for (int ki = 0; ki < 4; ++ki) {
                const float4 x0 = *(const float4*)&h2l[(kc * 4 + ki) * 12 + w0];
                float xv[4] = {x0.x, x0.y, x0.z, x0.w};
#pragma unroll
                for (int j = 0; j < 4; ++j) {
                    ar[j] = fmaf(wrk[ki], xv[j], ar[j]);
                    az[j] = fmaf(wzk[ki], xv[j], az[j]);
                    ah[j] = fmaf(wnk[ki], xv[j], ah[j]);
                }
            }
        }
        __syncthreads();
#pragma unroll
        for (int j = 0; j < 4; ++j) {
            float r = sigm(ar[j]);
            float z = sigm(az[j]);
            float n = tanh_f(ai[j] + r * ah[j]);
            h2r[j] = (1.f - z) * n + z * h2r[j];
        }
#pragma unroll
        for (int j = 0; j < 4; ++j) h2l[u * 12 + w0 + j] = h2r[j];
        __syncthreads();
    }

    for (int idx = tid; idx < 8 * 30; idx += 256) {
        int w = idx / 30, ff = idx - w * 30;
        float acc = b1[ff];
        for (int k = 0; k < 128; ++k) acc = fmaf(h2l[k * 12 + w], W1[ff * 128 + k], acc);
        fbuf[(seq * 2048 + wbase + w) * 32 + ff] = acc;
    }
}

// ------------------------------------------- pairwise sqdist -> E = exp(-D), padded
__global__ __launch_bounds__(256)
void k_pair(const float* __restrict__ fbuf, float* __restrict__ Ep) {
    __shared__ float f1t[64 * 33];
    __shared__ float f2t[64 * 33];
    const int tid = threadIdx.x;
    const int i0 = blockIdx.y * 64, j0 = blockIdx.x * 64;
    for (int e = tid; e < 64 * 32; e += 256) {
        int r = e >> 5, c = e & 31;
        f1t[r * 33 + c] = fbuf[(i0 + r) * 32 + c];
        f2t[r * 33 + c] = fbuf[(2048 + j0 + r) * 32 + c];
    }
    __syncthreads();
    const int tx = tid & 15, ty = tid >> 4;
    float acc[4][4];
#pragma unroll
    for (int r = 0; r < 4; ++r)
#pragma unroll
        for (int c = 0; c < 4; ++c) acc[r][c] = 0.f;
    for (int k = 0; k < 30; ++k) {
        float a[4], b[4];
#pragma unroll
        for (int r = 0; r < 4; ++r) a[r] = f1t[(ty * 4 + r) * 33 + k];
#pragma unroll
        for (int c = 0; c < 4; ++c) b[c] = f2t[(tx * 4 + c) * 33 + k];
#pragma unroll
        for (int r = 0; r < 4; ++r)
#pragma unroll
            for (int c = 0; c < 4; ++c) {
                float d = a[r] - b[c];
                acc[r][c] = fmaf(d, d, acc[r][c]);
            }
    }
#pragma unroll
    for (int r = 0; r < 4; ++r) {
        float4 v = make_float4(__expf(-acc[r][0]), __expf(-acc[r][1]),
                               __expf(-acc[r][2]), __expf(-acc[r][3]));
        *(float4*)&Ep[(size_t)(i0 + ty * 4 + r) * PD_LD + PD_OFF + j0 + tx * 4] = v;
    }
}

// ------------------------------------------- softDTW wavefront, EXP-DOMAIN
// R29 = R26 banked optimum (759.1us total; k_dtw 432us best draw).
// 2-col lane skew + per-group Sc overflow guard + slack tag 31 (lead
// ~19.5, floor ~18). Register E-tiles with distance-2 prefetch,
// compiler-scheduled -- measured better than PIN (R10), sched_barrier
// (R14), LDS+vmcnt (R23), and producer-consumer wave split (R27).
#define DTW_GROUP(G, CT)                                                         \
  {                                                                              \
    float inA, inB, dgl;                                                         \
    if (lane == 0) {                                                             \
        inA = sIn[2 * (G)]; inB = sIn[2 * (G) + 1];                              \
        dgl = ((G) == 0) ? carryA : sIn[2 * (G) - 1];                            \
    } else { inA = pA; inB = pB; dgl = dgPrev; }                                 \
    {   /* mid-macro overflow guard */                                           \
        float mnG = fminf(fminf(inA, inB), dgl);                                 \
        float lim = mnG + 100.f;                                                 \
        if (Sc > lim) {                                                          \
            int ddg = (int)fmaxf(lim - Sc, -2.0e9f);                             \
            W0 = ldexpf(W0, ddg); W1 = ldexpf(W1, ddg);                          \
            W2 = ldexpf(W2, ddg); W3 = ldexpf(W3, ddg);                          \
            Sc = lim;                                                            \
        }                                                                        \
    }                                                                            \
    float ua = fexp2(Sc - inA);                                                  \
    float ub = fexp2(Sc - inB);                                                  \
    float da = fexp2(Sc - dgl);                                                  \
    float eA0 = CT[0][2*(G)],   eA1 = CT[1][2*(G)];                              \
    float eA2 = CT[2][2*(G)],   eA3 = CT[3][2*(G)];                              \
    float eB0 = CT[0][2*(G)+1], eB1 = CT[1][2*(G)+1];                            \
    float eB2 = CT[2][2*(G)+1], eB3 = CT[3][2*(G)+1];                            \
    float oA0 = eA0 * (da + W0);                                                 \
    float oA1 = eA1 * (W0 + W1);                                                 \
    float oA2 = eA2 * (W1 + W2);                                                 \
    float oA3 = eA3 * (W2 + W3);                                                 \
    float a0 = fmaf(eA0, ua, oA0);                                               \
    float a1 = fmaf(eA1, a0, oA1);                                               \
    float a2 = fmaf(eA2, a1, oA2);                                               \
    float a3 = fmaf(eA3, a2, oA3);                                               \
    float oB0 = eB0 * (ua + a0);                                                 \
    float oB1 = eB1 * (a0 + a1);                                                 \
    float oB2 = eB2 * (a1 + a2);                                                 \
    float oB3 = eB3 * (a2 + a3);                                                 \
    float b0 = fmaf(eB0, ub, oB0);                                               \
    float b1 = fmaf(eB1, b0, oB1);                                               \
    float b2 = fmaf(eB2, b1, oB2);                                               \
    float b3 = fmaf(eB3, b2, oB3);                                               \
    W0 = b0; W1 = b1; W2 = b2; W3 = b3;                                          \
    float blogA = fminf(Sc - flog2(a3), INF2);                                   \
    float blogB = fminf(Sc - flog2(b3), INF2);                                   \
    blog[2 * (G)] = blogA; blog[2 * (G) + 1] = blogB;                            \
    float sA = __shfl_up(blogA, 1);                                              \
    float sB = __shfl_up(blogB, 1);                                              \
    dgPrev = pB; pA = sA; pB = sB;                                               \
    mnAcc = fminf(mnAcc, fminf(sA, sB));                                         \
  }

#define DTW_MACRO(CUR, PF, PVC, PVI, M)                                          \
  {                                                                              \
    const int m = (M);                                                           \
    { /* prefetch E tile for macro m+2 (float2: lane base is 8B-aligned) */      \
        int bs = 8 * (m + 2) - 2 * lane;                                         \
        bs = bs < -16 ? -16 : (bs > 2048 ? 2048 : bs);                           \
        _Pragma("unroll")                                                        \
        for (int r = 0; r < 4; ++r) {                                            \
            _Pragma("unroll")                                                    \
            for (int h = 0; h < 4; ++h) {                                        \
                float2 v = *(const float2*)(rp[r] + bs + 2 * h);                 \
                PF[r][2 * h] = v.x; PF[r][2 * h + 1] = v.y;                      \
            }                                                                    \
        }                                                                        \
    }                                                                            \
    if (b > 0 && lane == 0) {   /* issue boundary loads for macro m+3 */         \
        _Pragma("unroll")                                                        \
        for (int u = 0; u < 8; ++u) {                                            \
            int jc = 8 * (m + 3) + u; jc = jc > 2047 ? 2047 : jc;                \
            PVI[u] = __hip_atomic_load(&bIn[jc], __ATOMIC_RELAXED,               \
                                       __HIP_MEMORY_SCOPE_AGENT);                \
        }                                                                        \
    }                                                                            \
    float blog[8];                                                               \
    float mnAcc = INF2;                                                          \
    DTW_GROUP(0, CUR) DTW_GROUP(1, CUR) DTW_GROUP(2, CUR) DTW_GROUP(3, CUR)      \
    carryA = sIn[7];                                                             \
    if (lane == 63) {                                                            \
        if (b < 7) {                                                             \
            _Pragma("unroll")                                                    \
            for (int c = 0; c < 8; ++c) {                                        \
                int j = 8 * m + c - 126;                                         \
                if (j >= 0 && j < 2048) {                                        \
                    uint64_t pk = ((uint64_t)(uint32_t)j << 32) |                \
                                  (uint64_t)__float_as_uint(blog[c]);            \
                    (void)__hip_atomic_exchange(&bOut[j], pk, __ATOMIC_RELAXED,  \
                                                __HIP_MEMORY_SCOPE_AGENT);       \
                }                                                                \
            }                                                                    \
        } else if (m == 271) {   /* col 8*271+5-126 == 2047 */                   \
            res = blog[5];                                                       \
        }                                                                        \
    }                                                                            \
    if (b > 0 && lane == 0) {   /* consume ring slot PVC = boundary for m+1 */   \
        bool again = false;                                                      \
        _Pragma("unroll")                                                        \
        for (int u = 0; u < 8; ++u) {                                            \
            int jc = 8 * (m + 1) + u; jc = jc > 2047 ? 2047 : jc;                \
            if ((uint32_t)(PVC[u] >> 32) != (uint32_t)jc) again = true;          \
        }                                                                        \
        while (again) {   /* frontier contact: fine-grained backoff */           \
            __builtin_amdgcn_s_sleep(2);                                         \
            _Pragma("unroll")                                                    \
            for (int u = 0; u < 8; ++u) {                                        \
                int jc = 8 * (m + 1) + u; jc = jc > 2047 ? 2047 : jc;            \
                PVC[u] = __hip_atomic_load(&bIn[jc], __ATOMIC_RELAXED,           \
                                           __HIP_MEMORY_SCOPE_AGENT);            \
            }                                                                    \
            again = false;                                                       \
            _Pragma("unroll")                                                    \
            for (int u = 0; u < 8; ++u) {                                        \
                int jc = 8 * (m + 1) + u; jc = jc > 2047 ? 2047 : jc;            \
                if ((uint32_t)(PVC[u] >> 32) != (uint32_t)jc) again = true;      \
            }                                                                    \
        }                                                                        \
        _Pragma("unroll")                                                        \
        for (int u = 0; u < 8; ++u) sIn[u] = __uint_as_float((uint32_t)PVC[u]);  \
    }                                                                            \
    { /* scale update */                                                         \
        float mn = mnAcc;                                                        \
        if (lane == 0) {                                                         \
            if (b > 0) {                                                         \
                mn = sIn[0];                                                     \
                _Pragma("unroll")                                                \
                for (int c = 1; c < 8; ++c) mn = fminf(mn, sIn[c]);              \
            } else {                                                             \
                mn = INF2;                                                       \
            }                                                                    \
        }                                                                        \
        float wmax = fmaxf(fmaxf(W0, W1), fmaxf(W2, W3));                        \
        float Sc_new;                                                            \
        if (wmax > 0.f) {                                                        \
            int e = (int)((__float_as_uint(wmax) >> 23) & 0xFFu) - 127;          \
            Sc_new = fminf(Sc - (float)e, mn + 100.f);                           \
        } else {                                                                 \
            Sc_new = fminf(mn, 1e9f);                                            \
        }                                                                        \
        int dd = (int)fmaxf(fminf(Sc_new - Sc, 999.f), -999.f);                  \
        W0 = ldexpf(W0, dd); W1 = ldexpf(W1, dd);                                \
        W2 = ldexpf(W2, dd); W3 = ldexpf(W3, dd);                                \
        Sc = Sc_new;                                                             \
    }                                                                            \
  }

__global__ __launch_bounds__(64)
void k_dtw(const float* __restrict__ Ep, uint64_t* bndG, float* __restrict__ out) {
    const int b = blockIdx.x;
    const int lane = threadIdx.x;
    const int r0 = b * 256 + lane * 4;
    const uint64_t* bIn = bndG + (size_t)(b - 1) * 2048;
    uint64_t* bOut = bndG + (size_t)b * 2048;

    const float* rp[4];
#pragma unroll
    for (int r = 0; r < 4; ++r) rp[r] = Ep + (size_t)(r0 + r) * PD_LD + PD_OFF;

    float W0 = 0.f, W1 = 0.f, W2 = 0.f, W3 = 0.f;
    float Sc = 0.f;
    float carryA = (b == 0 && lane == 0) ? 0.f : INF2;  // seed: A(-1,-1)=0
    float res = 0.f;
    float pA = INF2, pB = INF2, dgPrev = INF2;          // pending shfl pair (log)
    float sIn[8];
#pragma unroll
    for (int c = 0; c < 8; ++c) sIn[c] = INF2;

    uint64_t pvs0[8], pvs1[8], pvs2[8];
#pragma unroll
    for (int u = 0; u < 8; ++u) { pvs0[u] = 0; pvs1[u] = 0; pvs2[u] = 0; }

    if (b > 0 && lane == 0) {
        // --- startup SLACK: wait until producer is ~19.5 macros ahead
        //     (col 31 written by b-1 at its macro 19 under the 2-col skew)
        {
            uint64_t p = __hip_atomic_load(&bIn[31], __ATOMIC_RELAXED,
                                           __HIP_MEMORY_SCOPE_AGENT);
            while ((uint32_t)(p >> 32) != 31u) {
                __builtin_amdgcn_s_sleep(8);
                p = __hip_atomic_load(&bIn[31], __ATOMIC_RELAXED,
                                      __HIP_MEMORY_SCOPE_AGENT);
            }
        }
        // --- blocking poll for macro-0 boundary (cols 0..7) + scale seed
        uint64_t pv[8];
        bool again = true;
        while (again) {
#pragma unroll
            for (int u = 0; u < 8; ++u)
                pv[u] = __hip_atomic_load(&bIn[u], __ATOMIC_RELAXED,
                                          __HIP_MEMORY_SCOPE_AGENT);
            again = false;
#pragma unroll
            for (int u = 0; u < 8; ++u)
                if ((uint32_t)(pv[u] >> 32) != (uint32_t)u) again = true;
            if (again) __builtin_amdgcn_s_sleep(2);
        }
        float mn = INF2;
#pragma unroll
        for (int u = 0; u < 8; ++u) {
            sIn[u] = __uint_as_float((uint32_t)pv[u]);
            mn = fminf(mn, sIn[u]);
        }
        Sc = fminf(mn, 1e9f);
        // --- prime ring: targets macro 1 (cols 8..15) and macro 2 (16..23)
#pragma unroll
        for (int u = 0; u < 8; ++u)
            pvs1[u] = __hip_atomic_load(&bIn[8 + u], __ATOMIC_RELAXED,
                                        __HIP_MEMORY_SCOPE_AGENT);
#pragma unroll
        for (int u = 0; u < 8; ++u)
            pvs2[u] = __hip_atomic_load(&bIn[16 + u], __ATOMIC_RELAXED,
                                        __HIP_MEMORY_SCOPE_AGENT);
    }

    float eT0[4][8], eT1[4][8], eT2[4][8];
#pragma unroll
    for (int tt = 0; tt < 2; ++tt) {   // preload tiles for macros 0 and 1
        int bs = 8 * tt - 2 * lane;
        bs = bs < -16 ? -16 : bs;
#pragma unroll
        for (int r = 0; r < 4; ++r) {
            float (*dst)[8] = tt ? eT1 : eT0;
#pragma unroll
            for (int h = 0; h < 4; ++h) {
                float2 v = *(const float2*)(rp[r] + bs + 2 * h);
                dst[r][2 * h] = v.x; dst[r][2 * h + 1] = v.y;
            }
        }
    }

    // 273 macro-steps of 8 cols (lane63 hits col 2047 at m=271)
    for (int mm = 0; mm < 273; mm += 3) {
        DTW_MACRO(eT0, eT2, pvs1, pvs0, mm);
        DTW_MACRO(eT1, eT0, pvs2, pvs1, mm + 1);
        DTW_MACRO(eT2, eT1, pvs0, pvs2, mm + 2);
    }

    if (b == 7 && lane == 63) out[0] = res * LN2;   // back to base-e units
}

// ------------------------------------------- launch
extern "C" void kernel_launch(void* const* d_in, const int* in_sizes, int n_in,
                              void* d_out, int out_size, void* d_ws, size_t ws_size,
                              hipStream_t stream) {
    const float* X    = (const float*)d_in[0];
    const float* Y    = (const float*)d_in[1];
    const float* Wih1 = (const float*)d_in[2];
    const float* Whh1 = (const float*)d_in[3];
    const float* bih1 = (const float*)d_in[4];
    const float* bhh1 = (const float*)d_in[5];
    const float* Wih2 = (const float*)d_in[6];
    const float* Whh2 = (const float*)d_in[7];
    const float* bih2 = (const float*)d_in[8];
    const float* bhh2 = (const float*)d_in[9];
    const float* W1   = (const float*)d_in[10];
    const float* b1   = (const float*)d_in[11];
    float* out = (float*)d_out;

    // Layout (floats). wt overlaps Ep's tail (dead after k_gru; k_pair
    // overwrites all of Ep afterwards). ~17.7 MB total.
    float* ws   = (float*)d_ws;
    float* fbuf = ws;                            // 131072 floats
    uint64_t* bndG = (uint64_t*)(ws + 131072);   // 7*2048 u64 = 28672 floats
    float* Ep   = ws + 131072 + 28672;           // 2048*2080 = 4259840 floats
    float* wt   = Ep + 4259840 - 175104;         // overlapped tail

    k_prep<<<684, 256, 0, stream>>>(Wih1, Whh1, Wih2, Whh2, wt);
    k_gru<<<512, 256, 0, stream>>>(X, Y, wt, bih1, bhh1, bih2, bhh2, W1, b1, fbuf);
    k_pair<<<dim3(32, 32), 256, 0, stream>>>(fbuf, Ep);
    k_dtw<<<8, 64, 0, stream>>>(Ep, bndG, out);
}